// Round 1
// baseline (207.732 us; speedup 1.0000x reference)
//
#include <hip/hip_runtime.h>

#define B_ 4
#define N_ 8192
#define M_ 2048
#define K_ 32
#define R2 0.16f

// ---------------- transpose [B,64,X] -> [B,X,64] ----------------
__global__ __launch_bounds__(256) void transpose64(const float* __restrict__ in,
                                                   float* __restrict__ out, int X) {
  __shared__ float tile[64][65];
  int b = blockIdx.y;
  int x0 = blockIdx.x * 64;
  int tx = threadIdx.x, ty = threadIdx.y;
  const float* src = in + (size_t)b * 64 * X + x0;
#pragma unroll
  for (int r = 0; r < 16; ++r) {
    int c = ty + r * 4;
    tile[c][tx] = src[(size_t)c * X + tx];
  }
  __syncthreads();
  float* dst = out + ((size_t)b * X + x0) * 64;
#pragma unroll
  for (int r = 0; r < 16; ++r) {
    int p = ty + r * 4;
    dst[(size_t)p * 64 + tx] = tile[tx][p];
  }
}

// ------------- y = [relu](W[64x64] @ x [+ bias]) over points, point-major -------------
__global__ __launch_bounds__(256) void matvec64(const float* __restrict__ in,  // [P,64]
                                                const float* __restrict__ W,   // [64,64] row-major
                                                const float* __restrict__ bias,
                                                float* __restrict__ out,       // [P,64]
                                                int do_relu, int has_bias) {
  __shared__ float xt[64][65];
  int t = threadIdx.x;
  size_t p0 = (size_t)blockIdx.x * 64;
  {
    int p = t >> 2, qd = t & 3;
    const float4* src = (const float4*)(in + (p0 + p) * 64 + qd * 16);
    float4 v0 = src[0], v1 = src[1], v2 = src[2], v3 = src[3];
    float* d = &xt[p][qd * 16];
    d[0] = v0.x; d[1] = v0.y; d[2] = v0.z; d[3] = v0.w;
    d[4] = v1.x; d[5] = v1.y; d[6] = v1.z; d[7] = v1.w;
    d[8] = v2.x; d[9] = v2.y; d[10] = v2.z; d[11] = v2.w;
    d[12] = v3.x; d[13] = v3.y; d[14] = v3.z; d[15] = v3.w;
  }
  __syncthreads();
  int j = t & 63;
  int g = __builtin_amdgcn_readfirstlane(t >> 6);  // wave id -> uniform channel group => s_loads for W
  float acc[16];
#pragma unroll
  for (int cc = 0; cc < 16; ++cc) acc[cc] = has_bias ? bias[g * 16 + cc] : 0.0f;
#pragma unroll 8
  for (int i = 0; i < 64; ++i) {
    float xv = xt[j][i];
#pragma unroll
    for (int cc = 0; cc < 16; ++cc)
      acc[cc] = fmaf(W[(g * 16 + cc) * 64 + i], xv, acc[cc]);
  }
  float* o = out + (p0 + j) * 64 + g * 16;
#pragma unroll
  for (int cc = 0; cc < 16; ++cc) {
    float v = acc[cc];
    if (do_relu) v = fmaxf(v, 0.0f);
    o[cc] = v;
  }
}

// ------------- xyz linear heads: PX = axW@p [-axb], PXS = xW@p [-xb] -------------
__global__ __launch_bounds__(256) void xyzprep(const float* __restrict__ pts,  // [P,3]
                                               int P,
                                               const float* __restrict__ axW, const float* __restrict__ axb,
                                               const float* __restrict__ xW, const float* __restrict__ xb,
                                               float* __restrict__ PX,   // [P,64]
                                               float* __restrict__ PXS,  // [P,16]
                                               int is_query) {
  int w = (int)((blockIdx.x * (size_t)blockDim.x + threadIdx.x) >> 6);
  int lane = threadIdx.x & 63;
  if (w >= P) return;
  float x = pts[w * 3 + 0], y = pts[w * 3 + 1], z = pts[w * 3 + 2];
  float v = axW[lane * 3 + 0] * x + axW[lane * 3 + 1] * y + axW[lane * 3 + 2] * z;
  if (is_query) v -= axb[lane];
  PX[(size_t)w * 64 + lane] = v;
  if (lane < 16) {
    float s = xW[lane * 3 + 0] * x + xW[lane * 3 + 1] * y + xW[lane * 3 + 2] * z;
    if (is_query) s -= xb[lane];
    PXS[(size_t)w * 16 + lane] = s;
  }
}

// ------------- ball query + weighted aggregation; 1 wave per query, lane = channel -------------
__global__ __launch_bounds__(256) void grouper_main(
    const float* __restrict__ xyz, const float* __restrict__ new_xyz,
    const float* __restrict__ PA, const float* __restrict__ PX,
    const float* __restrict__ P2, const float* __restrict__ PXS,
    const float* __restrict__ QA, const float* __restrict__ QX,
    const float* __restrict__ QXS,
    float* __restrict__ out) {  // -> d_out + B*M*3, layout [B,80,M]
  int wid = (int)((blockIdx.x * (size_t)blockDim.x + threadIdx.x) >> 6);
  int lane = threadIdx.x & 63;
  int b = wid >> 11;  // / M_
  int m = wid & (M_ - 1);
  const float* qc = new_xyz + ((size_t)b * M_ + m) * 3;
  float cx = qc[0], cy = qc[1], cz = qc[2];
  const float* xbp = xyz + (size_t)b * N_ * 3;

  // --- ball query: first K in-ball indices ascending; compact via ds_permute ---
  int idxreg = N_ - 1;  // default pad (matches reference's clip(N)=N-1 empty case)
  int cnt = 0;
  for (int base = 0; base < N_; base += 64) {
    int n = base + lane;
    float px0 = xbp[n * 3 + 0], py0 = xbp[n * 3 + 1], pz0 = xbp[n * 3 + 2];
    float dx = px0 - cx, dy = py0 - cy, dz = pz0 - cz;
    float d2 = dx * dx + dy * dy + dz * dz;
    bool inball = d2 < R2;
    unsigned long long mask = __ballot(inball);
    int pop = __popcll(mask);
    int before = __popcll(mask & ((1ULL << lane) - 1ULL));
    int pos = cnt + before;
    bool push = inball && (pos < K_);
    int dest = push ? pos : 63;  // dummy pushes collide on lane 63 (never a take target)
    int recv = __builtin_amdgcn_ds_permute(dest << 2, n);
    int newcnt = cnt + pop;
    bool take = (lane >= cnt) && (lane < min(newcnt, K_));
    if (take) idxreg = recv;
    cnt = newcnt;
    if (cnt >= K_) break;
  }
  int nneigh = min(cnt, K_);
  int first = __shfl(idxreg, 0);
  if (nneigh > 0 && lane >= nneigh) idxreg = first;  // pad with first neighbor
  float idn_mask = (nneigh > 0) ? 1.0f : 0.0f;

  size_t qb = (size_t)b * M_ + m;
  float QAm = QA[qb * 64 + lane];
  float QXm = QX[qb * 64 + lane];
  float QXSm = (lane < 16) ? QXS[qb * 16 + lane] : 0.0f;

  float accS = 0.0f, Rsum = 0.0f, nxmax = 0.0f;
#pragma unroll 4
  for (int k = 0; k < K_; ++k) {
    int n = __shfl(idxreg, k);
    size_t pb = (size_t)b * N_ + n;
    float pa = PA[pb * 64 + lane];
    float pxv = PX[pb * 64 + lane];
    float h2 = P2[pb * 64 + lane];
    float gx = xbp[n * 3 + 0] - cx, gy = xbp[n * 3 + 1] - cy, gz = xbp[n * 3 + 2] - cz;
    float dist = sqrtf(gx * gx + gy * gy + gz * gz);
    float r = 1.0f / (dist + 1e-8f);
    float idnv = (k < nneigh) ? 1.0f : (nneigh > 0 ? 0.0f : 1.0f);
    r = r / idnv;  // matches reference inf semantics for padded slots
    float fd = fmaxf(QAm - pa, 0.0f);          // relu(afW@(q-g)+afb)
    float sd = fmaxf(pxv - QXm, 0.0f);         // relu(axW@g_xyz+axb)
    float bi = fd * sd;
    accS = fmaf(r, h2 * bi, accS);
    Rsum += r;
    if (lane < 16) {
      float v = fmaxf(PXS[pb * 16 + lane] - QXSm, 0.0f);  // relu(xW@g_xyz+xb)
      nxmax = fmaxf(nxmax, v);
    }
  }
  float nf = (accS / Rsum) * idn_mask;
  float* ob = out + (size_t)b * 80 * M_;
  ob[(size_t)(16 + lane) * M_ + m] = nf;
  if (lane < 16) ob[(size_t)lane * M_ + m] = nxmax;
}

extern "C" void kernel_launch(void* const* d_in, const int* in_sizes, int n_in,
                              void* d_out, int out_size, void* d_ws, size_t ws_size,
                              hipStream_t stream) {
  const float* xyz   = (const float*)d_in[0];
  const float* nxyz  = (const float*)d_in[1];
  const float* feats = (const float*)d_in[2];
  const float* qfeat = (const float*)d_in[3];
  const float* qW  = (const float*)d_in[4];
  const float* qb  = (const float*)d_in[5];
  const float* afW = (const float*)d_in[6];
  const float* afb = (const float*)d_in[7];
  const float* axW = (const float*)d_in[8];
  const float* axb = (const float*)d_in[9];
  const float* mW1 = (const float*)d_in[10];
  const float* mb1 = (const float*)d_in[11];
  const float* mW2 = (const float*)d_in[12];
  const float* mb2 = (const float*)d_in[13];
  const float* xW  = (const float*)d_in[14];
  const float* xb  = (const float*)d_in[15];

  float* ws = (float*)d_ws;
  size_t off = 0;
  float* featT = ws + off; off += (size_t)B_ * N_ * 64;  // later reused as P2
  float* P1    = ws + off; off += (size_t)B_ * N_ * 64;
  float* PA    = ws + off; off += (size_t)B_ * N_ * 64;
  float* PX    = ws + off; off += (size_t)B_ * N_ * 64;
  float* PXS   = ws + off; off += (size_t)B_ * N_ * 16;
  float* qfT   = ws + off; off += (size_t)B_ * M_ * 64;  // later reused as QA
  float* q     = ws + off; off += (size_t)B_ * M_ * 64;
  float* QX    = ws + off; off += (size_t)B_ * M_ * 64;
  float* QXS   = ws + off; off += (size_t)B_ * M_ * 16;
  if (ws_size < off * sizeof(float)) return;  // fail loudly (wrong output) rather than corrupt

  dim3 tb(64, 4);
  transpose64<<<dim3(N_ / 64, B_), tb, 0, stream>>>(feats, featT, N_);
  transpose64<<<dim3(M_ / 64, B_), tb, 0, stream>>>(qfeat, qfT, M_);

  matvec64<<<B_ * N_ / 64, 256, 0, stream>>>(featT, mW1, mb1, P1, 1, 1);   // P1 = relu(mW1 f + mb1)
  matvec64<<<B_ * N_ / 64, 256, 0, stream>>>(featT, afW, afb, PA, 0, 0);   // PA = afW f
  float* P2 = featT;
  matvec64<<<B_ * N_ / 64, 256, 0, stream>>>(P1, mW2, mb2, P2, 1, 1);      // P2 = relu(mW2 P1 + mb2)
  matvec64<<<B_ * M_ / 64, 256, 0, stream>>>(qfT, qW, qb, q, 1, 1);        // q  = relu(qW qf + qb)
  float* QA = qfT;
  matvec64<<<B_ * M_ / 64, 256, 0, stream>>>(q, afW, afb, QA, 0, 1);       // QA = afW q + afb

  xyzprep<<<(B_ * N_ * 64) / 256, 256, 0, stream>>>(xyz, B_ * N_, axW, axb, xW, xb, PX, PXS, 0);
  xyzprep<<<(B_ * M_ * 64) / 256, 256, 0, stream>>>(nxyz, B_ * M_, axW, axb, xW, xb, QX, QXS, 1);

  hipMemcpyAsync(d_out, nxyz, (size_t)B_ * M_ * 3 * sizeof(float),
                 hipMemcpyDeviceToDevice, stream);

  float* out_main = (float*)d_out + (size_t)B_ * M_ * 3;
  grouper_main<<<B_ * M_ / 4, 256, 0, stream>>>(xyz, nxyz, PA, PX, P2, PXS, QA, QX, QXS, out_main);
}

// Round 3
// 154.334 us; speedup vs baseline: 1.3460x; 1.3460x over previous
//
#include <hip/hip_runtime.h>

#define B_ 4
#define N_ 8192
#define M_ 2048
#define K_ 32
#define R2 0.16f

// ---------- fused point-side prep ----------
// PA = afW @ f              (no bias, no relu)      [B*N,64]
// P2 = relu(mW2 @ relu(mW1 @ f + mb1) + mb2)        [B*N,64]
// feats is channel-major [B,64,N]; tile 64 points per block, LDS-transposed.
__global__ __launch_bounds__(256) void pointprep(const float* __restrict__ feats,
                                                 const float* __restrict__ afW,
                                                 const float* __restrict__ mW1, const float* __restrict__ mb1,
                                                 const float* __restrict__ mW2, const float* __restrict__ mb2,
                                                 float* __restrict__ PA,
                                                 float* __restrict__ P2) {
  __shared__ float xt[64][65];   // [ch][pt]
  __shared__ float x2[64][65];
  int b = blockIdx.y, p0 = blockIdx.x * 64;
  int t = threadIdx.x, lane = t & 63;
  int g = __builtin_amdgcn_readfirstlane(t >> 6);  // wave id -> uniform -> W via s_loads
  const float* src = feats + ((size_t)b * 64 + g * 16) * N_ + p0 + lane;
#pragma unroll
  for (int cc = 0; cc < 16; ++cc)
    xt[g * 16 + cc][lane] = src[(size_t)cc * N_];
  __syncthreads();
  size_t orow = ((size_t)b * N_ + p0 + lane) * 64 + g * 16;
  {  // PA
    float acc[16];
#pragma unroll
    for (int cc = 0; cc < 16; ++cc) acc[cc] = 0.0f;
#pragma unroll 4
    for (int i = 0; i < 64; ++i) {
      float xv = xt[i][lane];
#pragma unroll
      for (int cc = 0; cc < 16; ++cc) acc[cc] = fmaf(afW[(g * 16 + cc) * 64 + i], xv, acc[cc]);
    }
    float4* o = (float4*)(PA + orow);
#pragma unroll
    for (int q = 0; q < 4; ++q)
      o[q] = make_float4(acc[4 * q], acc[4 * q + 1], acc[4 * q + 2], acc[4 * q + 3]);
  }
  {  // P1 -> LDS
    float acc[16];
#pragma unroll
    for (int cc = 0; cc < 16; ++cc) acc[cc] = mb1[g * 16 + cc];
#pragma unroll 4
    for (int i = 0; i < 64; ++i) {
      float xv = xt[i][lane];
#pragma unroll
      for (int cc = 0; cc < 16; ++cc) acc[cc] = fmaf(mW1[(g * 16 + cc) * 64 + i], xv, acc[cc]);
    }
#pragma unroll
    for (int cc = 0; cc < 16; ++cc) x2[g * 16 + cc][lane] = fmaxf(acc[cc], 0.0f);
  }
  __syncthreads();
  {  // P2
    float acc[16];
#pragma unroll
    for (int cc = 0; cc < 16; ++cc) acc[cc] = mb2[g * 16 + cc];
#pragma unroll 4
    for (int i = 0; i < 64; ++i) {
      float xv = x2[i][lane];
#pragma unroll
      for (int cc = 0; cc < 16; ++cc) acc[cc] = fmaf(mW2[(g * 16 + cc) * 64 + i], xv, acc[cc]);
    }
    float4* o = (float4*)(P2 + orow);
#pragma unroll
    for (int q = 0; q < 4; ++q)
      o[q] = make_float4(fmaxf(acc[4 * q], 0.0f), fmaxf(acc[4 * q + 1], 0.0f),
                         fmaxf(acc[4 * q + 2], 0.0f), fmaxf(acc[4 * q + 3], 0.0f));
  }
}

// ---------- fused query-side prep ----------
// QA = afW @ relu(qW @ qf + qb) + afb   [B*M,64]; also copies new_xyz -> d_out head.
__global__ __launch_bounds__(256) void queryprep(const float* __restrict__ qfeat,  // [B,64,M]
                                                 const float* __restrict__ qW, const float* __restrict__ qb,
                                                 const float* __restrict__ afW, const float* __restrict__ afb,
                                                 const float* __restrict__ new_xyz,
                                                 float* __restrict__ QA,
                                                 float* __restrict__ outhead) {
  __shared__ float xt[64][65];
  __shared__ float x2[64][65];
  int b = blockIdx.y, p0 = blockIdx.x * 64;
  int t = threadIdx.x, lane = t & 63;
  int g = __builtin_amdgcn_readfirstlane(t >> 6);
  const float* src = qfeat + ((size_t)b * 64 + g * 16) * M_ + p0 + lane;
#pragma unroll
  for (int cc = 0; cc < 16; ++cc)
    xt[g * 16 + cc][lane] = src[(size_t)cc * M_];
  // new_xyz passthrough (independent of barriers)
  if (t < 192) {
    size_t o = (size_t)(b * M_ + p0) * 3 + t;
    outhead[o] = new_xyz[o];
  }
  __syncthreads();
  {  // q = relu(qW f + qb) -> LDS
    float acc[16];
#pragma unroll
    for (int cc = 0; cc < 16; ++cc) acc[cc] = qb[g * 16 + cc];
#pragma unroll 4
    for (int i = 0; i < 64; ++i) {
      float xv = xt[i][lane];
#pragma unroll
      for (int cc = 0; cc < 16; ++cc) acc[cc] = fmaf(qW[(g * 16 + cc) * 64 + i], xv, acc[cc]);
    }
#pragma unroll
    for (int cc = 0; cc < 16; ++cc) x2[g * 16 + cc][lane] = fmaxf(acc[cc], 0.0f);
  }
  __syncthreads();
  {  // QA = afW q + afb
    float acc[16];
#pragma unroll
    for (int cc = 0; cc < 16; ++cc) acc[cc] = afb[g * 16 + cc];
#pragma unroll 4
    for (int i = 0; i < 64; ++i) {
      float xv = x2[i][lane];
#pragma unroll
      for (int cc = 0; cc < 16; ++cc) acc[cc] = fmaf(afW[(g * 16 + cc) * 64 + i], xv, acc[cc]);
    }
    float4* o = (float4*)(QA + ((size_t)b * M_ + p0 + lane) * 64 + g * 16);
#pragma unroll
    for (int q = 0; q < 4; ++q)
      o[q] = make_float4(acc[4 * q], acc[4 * q + 1], acc[4 * q + 2], acc[4 * q + 3]);
  }
}

// ---------- ball query + aggregation; 1 wave/query, lane = channel ----------
__global__ __launch_bounds__(256) void grouper_main(
    const float* __restrict__ xyz, const float* __restrict__ new_xyz,
    const float* __restrict__ PA, const float* __restrict__ P2,
    const float* __restrict__ QA,
    const float* __restrict__ axW, const float* __restrict__ axb,
    const float* __restrict__ xW, const float* __restrict__ xb,
    float* __restrict__ out) {  // -> d_out + B*M*3, layout [B,80,M]
  int wid = (int)((blockIdx.x * (size_t)blockDim.x + threadIdx.x) >> 6);
  int lane = threadIdx.x & 63;
  int b = wid >> 11;
  int m = wid & (M_ - 1);
  const float* qc = new_xyz + ((size_t)b * M_ + m) * 3;
  float cx = qc[0], cy = qc[1], cz = qc[2];
  const float* xbp = xyz + (size_t)b * N_ * 3;

  // --- ball query: compact (idx, gx, gy, gz, d2) for first K in-ball points ---
  int idxreg = N_ - 1;
  float gxr = 0.f, gyr = 0.f, gzr = 0.f, d2r = 0.f;
  int cnt = 0;
  for (int base = 0; base < N_; base += 64) {
    int n = base + lane;
    const float* pp = xbp + 3 * n;
    float dx = pp[0] - cx, dy = pp[1] - cy, dz = pp[2] - cz;
    float d2 = dx * dx + dy * dy + dz * dz;
    bool inball = d2 < R2;
    unsigned long long mask = __ballot(inball);
    int pop = __popcll(mask);
    int before = __builtin_amdgcn_mbcnt_hi((unsigned)(mask >> 32),
                 __builtin_amdgcn_mbcnt_lo((unsigned)mask, 0));
    int pos = cnt + before;
    bool push = inball && (pos < K_);
    int dest = (push ? pos : 63) << 2;  // dummies collide on lane 63 (never taken)
    int rI = __builtin_amdgcn_ds_permute(dest, n);
    int rX = __builtin_amdgcn_ds_permute(dest, __float_as_int(dx));
    int rY = __builtin_amdgcn_ds_permute(dest, __float_as_int(dy));
    int rZ = __builtin_amdgcn_ds_permute(dest, __float_as_int(dz));
    int rD = __builtin_amdgcn_ds_permute(dest, __float_as_int(d2));
    int newcnt = cnt + pop;
    if ((lane >= cnt) && (lane < min(newcnt, K_))) {
      idxreg = rI; gxr = __int_as_float(rX); gyr = __int_as_float(rY);
      gzr = __int_as_float(rZ); d2r = __int_as_float(rD);
    }
    cnt = newcnt;
    if (cnt >= K_) break;
  }
  int nneigh = min(cnt, K_);
  if (nneigh == 0) {  // unreachable for this data; reference gathers point N-1
    const float* pp = xbp + 3 * (N_ - 1);
    float dx = pp[0] - cx, dy = pp[1] - cy, dz = pp[2] - cz;
    if (lane == 0) {
      idxreg = N_ - 1; gxr = dx; gyr = dy; gzr = dz;
      d2r = dx * dx + dy * dy + dz * dz;
    }
  }
  int padn = max(nneigh, 1);
  {  // pad slots >= padn with slot 0 (CUDA ball_query pad-with-first semantics)
    int i0 = __shfl(idxreg, 0);
    float x0 = __shfl(gxr, 0), y0 = __shfl(gyr, 0), z0 = __shfl(gzr, 0), d0 = __shfl(d2r, 0);
    if (lane >= padn) { idxreg = i0; gxr = x0; gyr = y0; gzr = z0; d2r = d0; }
  }
  float idn_mask = (nneigh > 0) ? 1.0f : 0.0f;

  size_t qb64 = ((size_t)b * M_ + m) * 64;
  float QAm = QA[qb64 + lane];
  float ax0 = axW[lane * 3 + 0], ax1 = axW[lane * 3 + 1], ax2 = axW[lane * 3 + 2];
  float axbv = axb[lane];
  float xw0 = 0.f, xw1 = 0.f, xw2 = 0.f, xbv = 0.f;
  if (lane < 16) { xw0 = xW[lane * 3 + 0]; xw1 = xW[lane * 3 + 1]; xw2 = xW[lane * 3 + 2]; xbv = xb[lane]; }

  const float* PAb = PA + (size_t)b * N_ * 64;
  const float* P2b = P2 + (size_t)b * N_ * 64;

  float accS = 0.f, Rsum = 0.f, nxmax = 0.f;
#pragma unroll 8
  for (int k = 0; k < K_; ++k) {
    int n = __builtin_amdgcn_readlane(idxreg, k);                         // uniform -> SGPR
    float gx = __int_as_float(__builtin_amdgcn_readlane(__float_as_int(gxr), k));
    float gy = __int_as_float(__builtin_amdgcn_readlane(__float_as_int(gyr), k));
    float gz = __int_as_float(__builtin_amdgcn_readlane(__float_as_int(gzr), k));
    float d2 = __int_as_float(__builtin_amdgcn_readlane(__float_as_int(d2r), k));
    float pa = PAb[(size_t)n * 64 + lane];                                 // coalesced
    float h2 = P2b[(size_t)n * 64 + lane];
    float dist = __builtin_amdgcn_sqrtf(d2);
    float r = __builtin_amdgcn_rcpf(dist + 1e-8f);
    float fd = fmaxf(QAm - pa, 0.f);                                       // relu(afW@(q-g)+afb)
    float sd = fmaxf(fmaf(ax0, gx, fmaf(ax1, gy, fmaf(ax2, gz, axbv))), 0.f);  // relu(axW@g+axb)
    accS = fmaf(r, h2 * fd * sd, accS);
    Rsum += r;
    float v = fmaxf(fmaf(xw0, gx, fmaf(xw1, gy, fmaf(xw2, gz, xbv))), 0.f);
    nxmax = fmaxf(nxmax, v);
  }
  float nf = (accS / Rsum) * idn_mask;
  float* ob = out + (size_t)b * 80 * M_;
  ob[(size_t)(16 + lane) * M_ + m] = nf;
  if (lane < 16) ob[(size_t)lane * M_ + m] = nxmax;
}

extern "C" void kernel_launch(void* const* d_in, const int* in_sizes, int n_in,
                              void* d_out, int out_size, void* d_ws, size_t ws_size,
                              hipStream_t stream) {
  const float* xyz   = (const float*)d_in[0];
  const float* nxyz  = (const float*)d_in[1];
  const float* feats = (const float*)d_in[2];
  const float* qfeat = (const float*)d_in[3];
  const float* qW  = (const float*)d_in[4];
  const float* qb  = (const float*)d_in[5];
  const float* afW = (const float*)d_in[6];
  const float* afb = (const float*)d_in[7];
  const float* axW = (const float*)d_in[8];
  const float* axb = (const float*)d_in[9];
  const float* mW1 = (const float*)d_in[10];
  const float* mb1 = (const float*)d_in[11];
  const float* mW2 = (const float*)d_in[12];
  const float* mb2 = (const float*)d_in[13];
  const float* xW  = (const float*)d_in[14];
  const float* xb  = (const float*)d_in[15];

  float* ws = (float*)d_ws;
  size_t off = 0;
  float* PA = ws + off; off += (size_t)B_ * N_ * 64;
  float* P2 = ws + off; off += (size_t)B_ * N_ * 64;
  float* QA = ws + off; off += (size_t)B_ * M_ * 64;
  if (ws_size < off * sizeof(float)) return;  // fail loudly rather than corrupt

  pointprep<<<dim3(N_ / 64, B_), 256, 0, stream>>>(feats, afW, mW1, mb1, mW2, mb2, PA, P2);

  float* outhead = (float*)d_out;  // new_xyz passthrough lives at d_out[0 : B*M*3]
  queryprep<<<dim3(M_ / 64, B_), 256, 0, stream>>>(qfeat, qW, qb, afW, afb, nxyz, QA, outhead);

  float* out_main = (float*)d_out + (size_t)B_ * M_ * 3;
  grouper_main<<<B_ * M_ / 4, 256, 0, stream>>>(xyz, nxyz, PA, P2, QA,
                                                axW, axb, xW, xb, out_main);
}

// Round 5
// 136.741 us; speedup vs baseline: 1.5192x; 1.1287x over previous
//
#include <hip/hip_runtime.h>

#define B_ 4
#define N_ 8192
#define M_ 2048
#define K_ 32
#define R2 0.16f

__device__ __forceinline__ float readlane_f(float v, int k) {
  return __int_as_float(__builtin_amdgcn_readlane(__float_as_int(v), k));
}

// ---------- fused prep: point-side + query-side in one dispatch ----------
// blocks [0, N/64):        PH[b*N+p][ch*2+{0,1}] = { afW@f , relu(mW2@relu(mW1@f+mb1)+mb2) }
// blocks [N/64, N/64+M/64): QA[b*M+m][ch] = afW@relu(qW@qf+qb)+afb ; also new_xyz -> d_out head
__global__ __launch_bounds__(256) void prep(
    const float* __restrict__ feats, const float* __restrict__ qfeat,
    const float* __restrict__ qW, const float* __restrict__ qb,
    const float* __restrict__ afW, const float* __restrict__ afb,
    const float* __restrict__ mW1, const float* __restrict__ mb1,
    const float* __restrict__ mW2, const float* __restrict__ mb2,
    const float* __restrict__ new_xyz,
    float* __restrict__ PH, float* __restrict__ QA, float* __restrict__ outhead) {
  __shared__ float xt[64][65];
  __shared__ float x2[64][65];
  int b = blockIdx.y;
  int t = threadIdx.x, lane = t & 63;
  int g = __builtin_amdgcn_readfirstlane(t >> 6);  // uniform wave id -> W rows via s_loads

  if (blockIdx.x < N_ / 64) {
    // ---- point side ----
    int p0 = blockIdx.x * 64;
    const float* src = feats + ((size_t)b * 64 + g * 16) * N_ + p0 + lane;
#pragma unroll
    for (int cc = 0; cc < 16; ++cc) xt[g * 16 + cc][lane] = src[(size_t)cc * N_];
    __syncthreads();
    float pa[16];
    {  // PA = afW @ f
#pragma unroll
      for (int cc = 0; cc < 16; ++cc) pa[cc] = 0.0f;
#pragma unroll 4
      for (int i = 0; i < 64; ++i) {
        float xv = xt[i][lane];
#pragma unroll
        for (int cc = 0; cc < 16; ++cc) pa[cc] = fmaf(afW[(g * 16 + cc) * 64 + i], xv, pa[cc]);
      }
    }
    {  // P1 = relu(mW1 f + mb1) -> LDS
      float acc[16];
#pragma unroll
      for (int cc = 0; cc < 16; ++cc) acc[cc] = mb1[g * 16 + cc];
#pragma unroll 4
      for (int i = 0; i < 64; ++i) {
        float xv = xt[i][lane];
#pragma unroll
        for (int cc = 0; cc < 16; ++cc) acc[cc] = fmaf(mW1[(g * 16 + cc) * 64 + i], xv, acc[cc]);
      }
#pragma unroll
      for (int cc = 0; cc < 16; ++cc) x2[g * 16 + cc][lane] = fmaxf(acc[cc], 0.0f);
    }
    __syncthreads();
    {  // P2 = relu(mW2 P1 + mb2); store interleaved with PA
      float h2[16];
#pragma unroll
      for (int cc = 0; cc < 16; ++cc) h2[cc] = mb2[g * 16 + cc];
#pragma unroll 4
      for (int i = 0; i < 64; ++i) {
        float xv = x2[i][lane];
#pragma unroll
        for (int cc = 0; cc < 16; ++cc) h2[cc] = fmaf(mW2[(g * 16 + cc) * 64 + i], xv, h2[cc]);
      }
      float4* o = (float4*)(PH + ((size_t)b * N_ + p0 + lane) * 128 + g * 32);
#pragma unroll
      for (int qd = 0; qd < 8; ++qd)
        o[qd] = make_float4(pa[2 * qd], fmaxf(h2[2 * qd], 0.0f),
                            pa[2 * qd + 1], fmaxf(h2[2 * qd + 1], 0.0f));
    }
  } else {
    // ---- query side ----
    int p0 = (blockIdx.x - N_ / 64) * 64;
    const float* src = qfeat + ((size_t)b * 64 + g * 16) * M_ + p0 + lane;
#pragma unroll
    for (int cc = 0; cc < 16; ++cc) xt[g * 16 + cc][lane] = src[(size_t)cc * M_];
    if (t < 192) {  // new_xyz passthrough
      size_t o = (size_t)(b * M_ + p0) * 3 + t;
      outhead[o] = new_xyz[o];
    }
    __syncthreads();
    {  // q = relu(qW f + qb) -> LDS
      float acc[16];
#pragma unroll
      for (int cc = 0; cc < 16; ++cc) acc[cc] = qb[g * 16 + cc];
#pragma unroll 4
      for (int i = 0; i < 64; ++i) {
        float xv = xt[i][lane];
#pragma unroll
        for (int cc = 0; cc < 16; ++cc) acc[cc] = fmaf(qW[(g * 16 + cc) * 64 + i], xv, acc[cc]);
      }
#pragma unroll
      for (int cc = 0; cc < 16; ++cc) x2[g * 16 + cc][lane] = fmaxf(acc[cc], 0.0f);
    }
    __syncthreads();
    {  // QA = afW q + afb
      float acc[16];
#pragma unroll
      for (int cc = 0; cc < 16; ++cc) acc[cc] = afb[g * 16 + cc];
#pragma unroll 4
      for (int i = 0; i < 64; ++i) {
        float xv = x2[i][lane];
#pragma unroll
        for (int cc = 0; cc < 16; ++cc) acc[cc] = fmaf(afW[(g * 16 + cc) * 64 + i], xv, acc[cc]);
      }
      float4* o = (float4*)(QA + ((size_t)b * M_ + p0 + lane) * 64 + g * 16);
#pragma unroll
      for (int q = 0; q < 4; ++q)
        o[q] = make_float4(acc[4 * q], acc[4 * q + 1], acc[4 * q + 2], acc[4 * q + 3]);
    }
  }
}

// ---------- ball query + aggregation; 1 wave/query, lane = channel ----------
__global__ __launch_bounds__(256) void grouper_main(
    const float* __restrict__ xyz, const float* __restrict__ new_xyz,
    const float* __restrict__ PH, const float* __restrict__ QA,
    const float* __restrict__ axW, const float* __restrict__ axb,
    const float* __restrict__ xW, const float* __restrict__ xb,
    float* __restrict__ out) {  // -> d_out + B*M*3, layout [B,80,M]
  int wid = (int)((blockIdx.x * (size_t)blockDim.x + threadIdx.x) >> 6);
  int lane = threadIdx.x & 63;
  int b = wid >> 11;
  int m = wid & (M_ - 1);
  const float* qc = new_xyz + ((size_t)b * M_ + m) * 3;
  float cx = qc[0], cy = qc[1], cz = qc[2];
  const float* xbp = xyz + (size_t)b * N_ * 3;

  // --- ball query: compact (idx, gx, gy, gz, d2) of first K in-ball points into lanes 0..K-1 ---
  int idxreg = N_ - 1;
  float gxr = 0.f, gyr = 0.f, gzr = 0.f, d2r = 0.f;
  int cnt = 0;
  for (int base = 0; base < N_; base += 64) {
    int n = base + lane;
    const float* pp = xbp + 3 * n;
    float dx = pp[0] - cx, dy = pp[1] - cy, dz = pp[2] - cz;
    float d2 = dx * dx + dy * dy + dz * dz;
    bool inball = d2 < R2;
    unsigned long long mask = __ballot(inball);
    int pop = __popcll(mask);
    int before = __builtin_amdgcn_mbcnt_hi((unsigned)(mask >> 32),
                 __builtin_amdgcn_mbcnt_lo((unsigned)mask, 0));
    int pos = cnt + before;
    bool push = inball && (pos < K_);
    int dest = (push ? pos : 63) << 2;  // dummies collide on lane 63 (never taken)
    int rI = __builtin_amdgcn_ds_permute(dest, n);
    int rX = __builtin_amdgcn_ds_permute(dest, __float_as_int(dx));
    int rY = __builtin_amdgcn_ds_permute(dest, __float_as_int(dy));
    int rZ = __builtin_amdgcn_ds_permute(dest, __float_as_int(dz));
    int rD = __builtin_amdgcn_ds_permute(dest, __float_as_int(d2));
    int newcnt = cnt + pop;
    if ((lane >= cnt) && (lane < min(newcnt, K_))) {
      idxreg = rI; gxr = __int_as_float(rX); gyr = __int_as_float(rY);
      gzr = __int_as_float(rZ); d2r = __int_as_float(rD);
    }
    cnt = newcnt;
    if (cnt >= K_) break;
  }
  int nneigh = min(cnt, K_);
  if (nneigh == 0) {  // unreachable for this data; reference gathers point N-1
    const float* pp = xbp + 3 * (N_ - 1);
    float dx = pp[0] - cx, dy = pp[1] - cy, dz = pp[2] - cz;
    if (lane == 0) {
      idxreg = N_ - 1; gxr = dx; gyr = dy; gzr = dz;
      d2r = dx * dx + dy * dy + dz * dz;
    }
  }
  int padn = max(nneigh, 1);
  {  // pad slots >= padn with slot 0 (CUDA ball_query pad-with-first semantics)
    int i0 = __shfl(idxreg, 0);
    float x0 = __shfl(gxr, 0), y0 = __shfl(gyr, 0), z0 = __shfl(gzr, 0), d0 = __shfl(d2r, 0);
    if (lane >= padn) { idxreg = i0; gxr = x0; gyr = y0; gzr = z0; d2r = d0; }
  }
  float idn_mask = (nneigh > 0) ? 1.0f : 0.0f;

  // per-lane reciprocal distance for the slot this lane holds (hoisted transcendentals)
  float rslot = __builtin_amdgcn_rcpf(__builtin_amdgcn_sqrtf(d2r) + 1e-8f);
  if (nneigh > 0 && lane >= nneigh && lane < K_) rslot = __builtin_huge_valf();  // r/idn=inf (unreachable path)
  // Rsum = sum of r over the K slots (wave tree-reduce; lanes >= K contribute 0)
  float Rsum;
  {
    float s = (lane < K_) ? rslot : 0.0f;
    s += __shfl_xor(s, 1);  s += __shfl_xor(s, 2);  s += __shfl_xor(s, 4);
    s += __shfl_xor(s, 8);  s += __shfl_xor(s, 16); s += __shfl_xor(s, 32);
    Rsum = s;
  }

  size_t qb64 = ((size_t)b * M_ + m) * 64;
  float QAm = QA[qb64 + lane];
  float ax0 = axW[lane * 3 + 0], ax1 = axW[lane * 3 + 1], ax2 = axW[lane * 3 + 2];
  float axbv = axb[lane];
  float xw0 = 0.f, xw1 = 0.f, xw2 = 0.f, xbv = 0.f;
  if (lane < 16) { xw0 = xW[lane * 3 + 0]; xw1 = xW[lane * 3 + 1]; xw2 = xW[lane * 3 + 2]; xbv = xb[lane]; }

  const float* PHb = PH + (size_t)b * N_ * 128;

  float accS = 0.f, nxmax = 0.f;
#pragma unroll
  for (int kg = 0; kg < 4; ++kg) {
    float2 v[8];
    float gxs[8], gys[8], gzs[8], rs[8];
#pragma unroll
    for (int j = 0; j < 8; ++j) {
      int k = kg * 8 + j;
      int n = __builtin_amdgcn_readlane(idxreg, k);   // uniform -> SGPR
      gxs[j] = readlane_f(gxr, k);
      gys[j] = readlane_f(gyr, k);
      gzs[j] = readlane_f(gzr, k);
      rs[j]  = readlane_f(rslot, k);
      v[j] = *(const float2*)(PHb + (size_t)n * 128 + lane * 2);  // coalesced dwordx2
    }
#pragma unroll
    for (int j = 0; j < 8; ++j) {
      float pa = v[j].x, h2 = v[j].y;
      float fd = fmaxf(QAm - pa, 0.f);                                           // relu(afW@(q-g)+afb)
      float sd = fmaxf(fmaf(ax0, gxs[j], fmaf(ax1, gys[j], fmaf(ax2, gzs[j], axbv))), 0.f);
      accS = fmaf(rs[j], h2 * fd * sd, accS);
      float nv = fmaxf(fmaf(xw0, gxs[j], fmaf(xw1, gys[j], fmaf(xw2, gzs[j], xbv))), 0.f);
      nxmax = fmaxf(nxmax, nv);
    }
  }
  float nf = (accS / Rsum) * idn_mask;
  float* ob = out + (size_t)b * 80 * M_;
  ob[(size_t)(16 + lane) * M_ + m] = nf;
  if (lane < 16) ob[(size_t)lane * M_ + m] = nxmax;
}

extern "C" void kernel_launch(void* const* d_in, const int* in_sizes, int n_in,
                              void* d_out, int out_size, void* d_ws, size_t ws_size,
                              hipStream_t stream) {
  const float* xyz   = (const float*)d_in[0];
  const float* nxyz  = (const float*)d_in[1];
  const float* feats = (const float*)d_in[2];
  const float* qfeat = (const float*)d_in[3];
  const float* qW  = (const float*)d_in[4];
  const float* qb  = (const float*)d_in[5];
  const float* afW = (const float*)d_in[6];
  const float* afb = (const float*)d_in[7];
  const float* axW = (const float*)d_in[8];
  const float* axb = (const float*)d_in[9];
  const float* mW1 = (const float*)d_in[10];
  const float* mb1 = (const float*)d_in[11];
  const float* mW2 = (const float*)d_in[12];
  const float* mb2 = (const float*)d_in[13];
  const float* xW  = (const float*)d_in[14];
  const float* xb  = (const float*)d_in[15];

  float* ws = (float*)d_ws;
  size_t off = 0;
  float* PH = ws + off; off += (size_t)B_ * N_ * 128;  // interleaved {PA, P2}
  float* QA = ws + off; off += (size_t)B_ * M_ * 64;
  if (ws_size < off * sizeof(float)) return;  // fail loudly rather than corrupt

  float* outhead = (float*)d_out;  // new_xyz passthrough at d_out[0 : B*M*3]
  prep<<<dim3(N_ / 64 + M_ / 64, B_), 256, 0, stream>>>(
      feats, qfeat, qW, qb, afW, afb, mW1, mb1, mW2, mb2, nxyz, PH, QA, outhead);

  float* out_main = (float*)d_out + (size_t)B_ * M_ * 3;
  grouper_main<<<B_ * M_ / 4, 256, 0, stream>>>(xyz, nxyz, PH, QA,
                                                axW, axb, xW, xb, out_main);
}